// Round 1
// baseline (576.873 us; speedup 1.0000x reference)
//
#include <hip/hip_runtime.h>
#include <math.h>

#define B_  16
#define C_  512
#define T_  8192
#define T4_ (T_/4)

// ---------------------------------------------------------------------------
// Kernel 1: per-(b,t) channel partial sums of x and x^2.
// grid = (T4/256, B, nchunk); 256 threads; each thread owns one float4 of t.
// Reads are float4-coalesced across t (stride-1). Channel loop is unrolled
// for memory-level parallelism.
// partial layout (float): [(b*nchunk + chunk)*2 + which][T], which: 0=s, 1=ss
// ---------------------------------------------------------------------------
__global__ void sums_kernel(const float* __restrict__ x,
                            float* __restrict__ partial,
                            int c_per_chunk, int nchunk) {
    int t4 = blockIdx.x * blockDim.x + threadIdx.x;   // 0..T4-1
    int b = blockIdx.y;
    int chunk = blockIdx.z;
    const float4* xb = (const float4*)x + ((size_t)(b * C_ + chunk * c_per_chunk)) * T4_;
    float4 s  = make_float4(0.f, 0.f, 0.f, 0.f);
    float4 ss = make_float4(0.f, 0.f, 0.f, 0.f);
    #pragma unroll 8
    for (int c = 0; c < c_per_chunk; ++c) {
        float4 v = xb[(size_t)c * T4_ + t4];
        s.x += v.x;       s.y += v.y;       s.z += v.z;       s.w += v.w;
        ss.x += v.x * v.x; ss.y += v.y * v.y; ss.z += v.z * v.z; ss.w += v.w * v.w;
    }
    size_t base = (size_t)(b * nchunk + chunk) * 2 * T4_;   // in float4 units
    ((float4*)partial)[base + t4]        = s;
    ((float4*)partial)[base + T4_ + t4]  = ss;
}

// ---------------------------------------------------------------------------
// Kernel 2: per-b inclusive scan over T of (s, ss); emits mean and rstd.
// grid = B blocks of 256 threads; each thread owns 32 contiguous t.
// Double-precision accumulation (strictly tighter than the fp32 np reference).
// ---------------------------------------------------------------------------
__global__ void scan_kernel(const float* __restrict__ partial,
                            float* __restrict__ meano,
                            float* __restrict__ rstdo,
                            int nchunk) {
    const int b   = blockIdx.x;
    const int tid = threadIdx.x;       // 256 threads
    const int PER = T_ / 256;          // 32
    const int t0  = tid * PER;

    float ls[32], lss[32];
    double tot_s = 0.0, tot_ss = 0.0;
    for (int i = 0; i < PER; ++i) {
        int t = t0 + i;
        float sv = 0.f, ssv = 0.f;
        for (int ch = 0; ch < nchunk; ++ch) {
            size_t base = (size_t)(b * nchunk + ch) * 2 * T_;
            sv  += partial[base + t];
            ssv += partial[base + T_ + t];
        }
        ls[i] = sv; lss[i] = ssv;
        tot_s += sv; tot_ss += ssv;
    }

    __shared__ double sh_s[256], sh_ss[256];
    sh_s[tid] = tot_s; sh_ss[tid] = tot_ss;
    __syncthreads();
    double pre_s = 0.0, pre_ss = 0.0;
    for (int j = 0; j < tid; ++j) { pre_s += sh_s[j]; pre_ss += sh_ss[j]; }

    double run_s = pre_s, run_ss = pre_ss;
    for (int i = 0; i < PER; ++i) {
        run_s  += (double)ls[i];
        run_ss += (double)lss[i];
        int t = t0 + i;
        double div = 512.0 * (double)(t + 1);   // DIV_CONST * (t+1)
        double m   = run_s / div;
        double msq = run_ss / div;
        double var = msq - m * m;
        double r   = 1.0 / sqrt(var + 1e-8);    // EPS
        meano[b * T_ + t] = (float)m;
        rstdo[b * T_ + t] = (float)r;
    }
}

// ---------------------------------------------------------------------------
// Kernel 3: out = (x - mean[b,t]) * rstd[b,t] * gains[c] + bias[c]
// One float4 per thread; all index math is shifts (pow-2 dims).
// ---------------------------------------------------------------------------
__global__ void norm_kernel(const float* __restrict__ x,
                            const float* __restrict__ gains,
                            const float* __restrict__ bias,
                            const float* __restrict__ meanv,
                            const float* __restrict__ rstdv,
                            float* __restrict__ out) {
    int i  = blockIdx.x * blockDim.x + threadIdx.x;  // 0 .. B*C*T4-1 (16.7M)
    int t4 = i & (T4_ - 1);
    int bc = i >> 11;            // / T4_ (2048)
    int c  = bc & (C_ - 1);
    int b  = bc >> 9;            // / C_ (512)

    float4 xv = ((const float4*)x)[i];
    float4 mv = ((const float4*)meanv)[b * T4_ + t4];
    float4 rv = ((const float4*)rstdv)[b * T4_ + t4];
    float g  = gains[c];
    float bi = bias[c];

    float4 o;
    o.x = (xv.x - mv.x) * rv.x * g + bi;
    o.y = (xv.y - mv.y) * rv.y * g + bi;
    o.z = (xv.z - mv.z) * rv.z * g + bi;
    o.w = (xv.w - mv.w) * rv.w * g + bi;
    ((float4*)out)[i] = o;
}

extern "C" void kernel_launch(void* const* d_in, const int* in_sizes, int n_in,
                              void* d_out, int out_size, void* d_ws, size_t ws_size,
                              hipStream_t stream) {
    const float* x     = (const float*)d_in[0];
    const float* gains = (const float*)d_in[1];
    const float* bias  = (const float*)d_in[2];
    float* out = (float*)d_out;
    float* ws  = (float*)d_ws;

    const size_t BT = (size_t)B_ * T_;

    // ws layout: [mean BT][rstd BT][partials B*nchunk*2*T]
    int nchunk = 8;
    while (nchunk > 1 &&
           ws_size < (2 * BT + (size_t)B_ * nchunk * 2 * T_) * sizeof(float)) {
        nchunk >>= 1;
    }
    float* meanv   = ws;
    float* rstdv   = ws + BT;
    float* partial = ws + 2 * BT;
    int c_per_chunk = C_ / nchunk;

    dim3 g1(T4_ / 256, B_, nchunk);
    sums_kernel<<<g1, 256, 0, stream>>>(x, partial, c_per_chunk, nchunk);

    scan_kernel<<<B_, 256, 0, stream>>>(partial, meanv, rstdv, nchunk);

    int total4 = B_ * C_ * T4_;            // 16,777,216
    norm_kernel<<<total4 / 256, 256, 0, stream>>>(x, gains, bias, meanv, rstdv, out);
}